// Round 4
// baseline (314.232 us; speedup 1.0000x reference)
//
#include <hip/hip_runtime.h>
#include <hip/hip_bf16.h>
#include <math.h>

constexpr int NB  = 16;
constexpr int NT  = 1024;
constexpr int ND  = 128;
constexpr int NH  = 8;
constexpr int NHS = 16;
constexpr int NDH = 512;
constexpr long NBT = (long)NB * NT;   // 16384 tokens
constexpr unsigned NBLK = 512;        // fused grid size (2/CU x 256 CU)

typedef __attribute__((ext_vector_type(8))) short short8;
typedef __attribute__((ext_vector_type(4))) float f32x4;
typedef __attribute__((ext_vector_type(16))) float f32x16;
typedef __attribute__((ext_vector_type(4))) unsigned short us4;

__device__ __forceinline__ unsigned short f2bf(float f) {
    __hip_bfloat16 h = __float2bfloat16(f);
    return *(unsigned short*)&h;
}

// f32[8] -> bf16x8 fragment (RNE packed converts)
__device__ __forceinline__ short8 cvt8(const float* p) {
    const float4 f0 = *(const float4*)p;
    const float4 f1 = *(const float4*)(p + 4);
    union { short8 s; __hip_bfloat162 h[4]; } u;
    u.h[0] = __float22bfloat162_rn(make_float2(f0.x, f0.y));
    u.h[1] = __float22bfloat162_rn(make_float2(f0.z, f0.w));
    u.h[2] = __float22bfloat162_rn(make_float2(f1.x, f1.y));
    u.h[3] = __float22bfloat162_rn(make_float2(f1.z, f1.w));
    return u.s;
}

// fast GELU (tanh form, exp2-based): max |err| ~1e-3, under bf16 noise.
__device__ __forceinline__ float fast_gelu(float y) {
    const float t = y * y;
    const float u = __builtin_fmaf(y * 0.044715f, t, y);
    const float e = __builtin_amdgcn_exp2f(u * -2.302118131f); // -2*sqrt(2/pi)*log2(e)
    return y * __builtin_amdgcn_rcpf(1.0f + e);
}

// Manual grid barrier (single-use counter, pre-zeroed by hipMemsetAsync).
// Co-residency of all 512 blocks is forced by LDS (59392B -> max 2/CU) and
// __launch_bounds__(256,2) (VGPR<=256 -> 2 blocks/CU fit), grid = 2x256 CU.
// Device-scope release (threadfence+atomicAdd) / acquire (spin load+fence)
// handles cross-XCD L2 non-coherence. Fuel-limited: fails loud, never hangs.
__device__ __forceinline__ void gbar(unsigned* ctr) {
    __syncthreads();
    if (threadIdx.x == 0) {
        __threadfence();                 // release: my global writes visible
        atomicAdd(ctr, 1u);              // device-scope by default (m20)
        int fuel = 50000000;
        while (__hip_atomic_load(ctr, __ATOMIC_RELAXED, __HIP_MEMORY_SCOPE_AGENT) < NBLK
               && --fuel > 0) {
            __builtin_amdgcn_s_sleep(16);
        }
        __threadfence();                 // acquire: others' writes visible
    }
    __syncthreads();
}

// ============================================================================
// k_fused: the whole block in ONE kernel, manual grid barriers between phases.
//   phase 0: weight transposes (blocks 0..191)
//   phase 1: QKV GEMM (512 token-tiles)
//   phase 2: 32x32-MFMA flash attention (2 (bh,sub) units per block,
//            paired sub/(7-sub) for balance, XCD-pinned bh = bid&127)
//   phase 3: proj + LN1 + mlp1 + GELU + mlp2 + LN2 (512 token-tiles)
// LDS: one 59392 B arena, re-carved per phase (max = tail: 16896+8704+33792).
// ============================================================================
__global__ __launch_bounds__(256, 2) void k_fused(
    const float* __restrict__ x,
    const float* __restrict__ Wq, const float* __restrict__ bq,
    const float* __restrict__ Wk, const float* __restrict__ bk,
    const float* __restrict__ Wv, const float* __restrict__ bv,
    const float* __restrict__ Wp, const float* __restrict__ bp,
    const float* __restrict__ W1, const float* __restrict__ b1,
    const float* __restrict__ W2, const float* __restrict__ b2,
    const float* __restrict__ g1, const float* __restrict__ be1,
    const float* __restrict__ g2, const float* __restrict__ be2,
    __hip_bfloat16* __restrict__ Wqkvt, __hip_bfloat16* __restrict__ Wpt,
    __hip_bfloat16* __restrict__ W1t,  __hip_bfloat16* __restrict__ W2t,
    __hip_bfloat16* __restrict__ qb,   __hip_bfloat16* __restrict__ kb,
    __hip_bfloat16* __restrict__ vtb,  __hip_bfloat16* __restrict__ attb,
    unsigned* __restrict__ bars,
    float* __restrict__ out)
{
    __shared__ __align__(16) char smem[59392];
    const int bid  = blockIdx.x;
    const int tid  = threadIdx.x;
    const int w    = tid >> 6;
    const int lane = tid & 63;
    const int sL   = lane & 15;
    const int quad = lane >> 4;

    // ================= phase 0: weight prep (blocks 0..191) =================
    if (bid < 192) {
        us4 v;
        if (bid < 48) {           // Wqkvt: [384][128] <- Wq/Wk/Wv [8][128][16]
            const int i0 = bid * 1024 + tid * 4;
            const int n = i0 >> 7, d0 = i0 & 127;
            const int sec = n >> 7, m = n & 127;
            const float* W = (sec == 0) ? Wq : (sec == 1) ? Wk : Wv;
            const float* src = W + (m >> 4) * 2048 + (m & 15);
            #pragma unroll
            for (int j = 0; j < 4; ++j) v[j] = f2bf(src[(d0 + j) * 16]);
            *(us4*)((unsigned short*)Wqkvt + i0) = v;
        } else if (bid < 64) {    // Wpt: 16384
            const int i0 = (bid - 48) * 1024 + tid * 4;
            const int n = i0 >> 7, d0 = i0 & 127;
            #pragma unroll
            for (int j = 0; j < 4; ++j) v[j] = f2bf(Wp[(d0 + j) * 128 + n]);
            *(us4*)((unsigned short*)Wpt + i0) = v;
        } else if (bid < 128) {   // W1t: 65536
            const int i0 = (bid - 64) * 1024 + tid * 4;
            const int n = i0 >> 7, d0 = i0 & 127;
            #pragma unroll
            for (int j = 0; j < 4; ++j) v[j] = f2bf(W1[(d0 + j) * 512 + n]);
            *(us4*)((unsigned short*)W1t + i0) = v;
        } else {                  // W2t: 65536
            const int i0 = (bid - 128) * 1024 + tid * 4;
            const int n = i0 >> 9, k0 = i0 & 511;
            #pragma unroll
            for (int j = 0; j < 4; ++j) v[j] = f2bf(W2[(k0 + j) * 128 + n]);
            *(us4*)((unsigned short*)W2t + i0) = v;
        }
    }
    gbar(bars + 0);

    // ================= phase 1: QKV GEMM (512 tiles of 32 tokens) ===========
    {
        unsigned short* st = (unsigned short*)smem;    // 32*392 u16 = 25088 B
        const int tok0 = bid * 32;
        const unsigned short* W = (const unsigned short*)Wqkvt;

        short8 bx[2][4];
        #pragma unroll
        for (int tt = 0; tt < 2; ++tt)
            #pragma unroll
            for (int ks = 0; ks < 4; ++ks)
                bx[tt][ks] = cvt8(x + (size_t)(tok0 + tt * 16 + sL) * 128 + ks * 32 + quad * 8);

        f32x4 acc[6][2];
        #pragma unroll
        for (int ci = 0; ci < 6; ++ci)
            #pragma unroll
            for (int tt = 0; tt < 2; ++tt)
                acc[ci][tt] = (f32x4){0.f, 0.f, 0.f, 0.f};

        #pragma unroll
        for (int ks = 0; ks < 4; ++ks) {
            short8 aW[6];
            #pragma unroll
            for (int ci = 0; ci < 6; ++ci) {
                const int ct = w * 6 + ci;
                aW[ci] = *(const short8*)(W + (size_t)(ct * 16 + sL) * 128 + ks * 32 + quad * 8);
            }
            #pragma unroll
            for (int ci = 0; ci < 6; ++ci)
                #pragma unroll
                for (int tt = 0; tt < 2; ++tt)
                    acc[ci][tt] = __builtin_amdgcn_mfma_f32_16x16x32_bf16(aW[ci], bx[tt][ks], acc[ci][tt], 0, 0, 0);
        }

        const float qscale = 0.3606737602f;   // 0.25 * log2(e) folded into q
        #pragma unroll
        for (int ci = 0; ci < 6; ++ci) {
            const int ct = w * 6 + ci;
            const int kind = ct >> 3;
            const int ncc = (ct & 7) * 16 + quad * 4;
            const float4 bb = *(const float4*)(((kind == 0) ? bq : (kind == 1) ? bk : bv) + ncc);
            #pragma unroll
            for (int tt = 0; tt < 2; ++tt) {
                us4 v;
                #pragma unroll
                for (int r = 0; r < 4; ++r) {
                    float val = acc[ci][tt][r] + ((const float*)&bb)[r];
                    if (kind == 0) val *= qscale;
                    v[r] = f2bf(val);
                }
                *(us4*)(st + (tt * 16 + sL) * 392 + ct * 16 + quad * 4) = v;
            }
        }
        __syncthreads();

        const int b = tok0 >> 10, tt0 = tok0 & 1023;
        {   // q,k copy-out: thread = (h, tok); 32B contiguous each
            const int h = tid >> 5, tok = tid & 31;
            const unsigned short* sq = st + tok * 392 + h * 16;
            const unsigned short* sk = st + tok * 392 + 128 + h * 16;
            unsigned short* dq = (unsigned short*)qb + ((size_t)(b * 8 + h) * 1024 + tt0 + tok) * 16;
            unsigned short* dk = (unsigned short*)kb + ((size_t)(b * 8 + h) * 1024 + tt0 + tok) * 16;
            *(short8*)dq       = *(const short8*)sq;
            *(short8*)(dq + 8) = *(const short8*)(sq + 8);
            *(short8*)dk       = *(const short8*)sk;
            *(short8*)(dk + 8) = *(const short8*)(sk + 8);
        }
        if (tid < 128) {  // v copy-out (transposed): thread = (h,s)
            const int h = tid >> 4, s = tid & 15;
            unsigned short tmp[32];
            #pragma unroll
            for (int tok = 0; tok < 32; ++tok)
                tmp[tok] = st[tok * 392 + 256 + h * 16 + s];
            unsigned short* dv = (unsigned short*)vtb + ((size_t)(b * 8 + h) * 16 + s) * 1024 + tt0;
            #pragma unroll
            for (int j = 0; j < 4; ++j)
                *(short8*)(dv + j * 8) = *(const short8*)(tmp + j * 8);
        }
    }
    gbar(bars + 16);

    // ================= phase 2: attention (2 units per block) ===============
    // permlane32_swap(a,b): ret[0]=[a.lo32lanes|b.lo32lanes],
    //                       ret[1]=[a.hi32lanes|b.hi32lanes]
    {
        float* sp = (float*)smem + w * 512;     // per-wave o staging [32][16]
        const int col = lane & 31;
        const int hi  = lane >> 5;
        const int bh = bid & 127;
        const int spair = bid >> 7;             // 0..3
        const int b = bh >> 3, h = bh & 7;

        const unsigned short* qp = (const unsigned short*)qb  + (size_t)bh * NT * NHS;
        const unsigned short* kp = (const unsigned short*)kb  + (size_t)bh * NT * NHS;
        const unsigned short* vp = (const unsigned short*)vtb + (size_t)bh * NHS * NT;
        const unsigned short* vrow = vp + (size_t)(col & 15) * NT + hi * 8;

        f32x16 zc;
        #pragma unroll
        for (int r = 0; r < 16; ++r) zc[r] = 0.f;

        #pragma unroll 1
        for (int ui = 0; ui < 2; ++ui) {
            const int sub  = ui ? (7 - spair) : spair;
            const int tile = sub * 4 + w;
            const int t0 = tile * 32;

            const short8 bQ = *(const short8*)(qp + (size_t)(t0 + col) * NHS + hi * 8);

            f32x16 o;
            #pragma unroll
            for (int r = 0; r < 16; ++r) o[r] = 0.f;
            float lp0 = 0.f, lp1 = 0.f, lp2 = 0.f, lp3 = 0.f;

            for (int c = 0; c <= tile; ++c) {
                const int u0 = c * 32;
                const short8 aK  = *(const short8*)(kp + (size_t)(u0 + col) * NHS + hi * 8);
                const short8 bV0 = *(const short8*)(vrow + u0);
                const short8 bV1 = *(const short8*)(vrow + u0 + 16);

                // S[k][q]: col = q = lane&31, k = (r&3)+8*(r>>2)+4*hi
                const f32x16 sT = __builtin_amdgcn_mfma_f32_32x32x16_bf16(aK, bQ, zc, 0, 0, 0);

                float p[16];
                if (c < tile) {
                    #pragma unroll
                    for (int r = 0; r < 16; ++r) p[r] = __builtin_amdgcn_exp2f(sT[r]);
                } else {                           // diagonal chunk: k<=q mask
                    const int kh = 4 * hi;
                    #pragma unroll
                    for (int r = 0; r < 16; ++r) {
                        const int kc = (r & 3) + 8 * (r >> 2) + kh;
                        const float e = __builtin_amdgcn_exp2f(sT[r]);
                        p[r] = (kc <= col) ? e : 0.f;
                    }
                }
                #pragma unroll
                for (int r = 0; r < 16; r += 4) {
                    lp0 += p[r]; lp1 += p[r + 1]; lp2 += p[r + 2]; lp3 += p[r + 3];
                }

                int d[8];
                #pragma unroll
                for (int i = 0; i < 8; ++i) {
                    __hip_bfloat162 hh = __float22bfloat162_rn(make_float2(p[2 * i], p[2 * i + 1]));
                    d[i] = *(int*)&hh;
                }
                auto s0 = __builtin_amdgcn_permlane32_swap(d[0], d[2], false, false);
                auto s1 = __builtin_amdgcn_permlane32_swap(d[1], d[3], false, false);
                auto s2 = __builtin_amdgcn_permlane32_swap(d[4], d[6], false, false);
                auto s3 = __builtin_amdgcn_permlane32_swap(d[5], d[7], false, false);
                union { int i[4]; short8 v; } A0, A1;
                A0.i[0] = s0[0]; A0.i[1] = s1[0]; A0.i[2] = s0[1]; A0.i[3] = s1[1];
                A1.i[0] = s2[0]; A1.i[1] = s3[0]; A1.i[2] = s2[1]; A1.i[3] = s3[1];

                o = __builtin_amdgcn_mfma_f32_32x32x16_bf16(A0.v, bV0, o, 0, 0, 0);
                o = __builtin_amdgcn_mfma_f32_32x32x16_bf16(A1.v, bV1, o, 0, 0, 0);
            }

            float lp = (lp0 + lp1) + (lp2 + lp3);
            lp += __shfl_xor(lp, 32);
            const float inv = 1.0f / lp;

            if (col < 16) {
                #pragma unroll
                for (int r = 0; r < 16; ++r) {
                    const int qr = (r & 3) + 8 * (r >> 2) + 4 * hi;
                    sp[qr * 16 + col] = o[r];
                }
            }
            __syncthreads();
            const float invq = __shfl(inv, lane >> 1);
            const float* rp = sp + (lane >> 1) * 16 + (lane & 1) * 8;
            const float4 va = *(const float4*)rp;
            const float4 vb = *(const float4*)(rp + 4);
            union { short8 v; unsigned short u[8]; } res;
            res.u[0] = f2bf(va.x * invq); res.u[1] = f2bf(va.y * invq);
            res.u[2] = f2bf(va.z * invq); res.u[3] = f2bf(va.w * invq);
            res.u[4] = f2bf(vb.x * invq); res.u[5] = f2bf(vb.y * invq);
            res.u[6] = f2bf(vb.z * invq); res.u[7] = f2bf(vb.w * invq);
            unsigned short* dst = (unsigned short*)attb +
                ((size_t)b * NT + t0 + (lane >> 1)) * ND + h * NHS + (lane & 1) * 8;
            *(short8*)dst = res.v;
            __syncthreads();    // sp reused by next unit
        }
    }
    gbar(bars + 32);

    // ===== phase 3: tail — proj + LN1 + mlp1 + GELU + mlp2 + LN2 ============
    {
        float (*ys)[132]    = (float(*)[132])smem;                    // 16896 B
        unsigned short* l1b = (unsigned short*)(smem + 16896);        //  8704 B
        unsigned short* midb= (unsigned short*)(smem + 16896 + 8704); // 33792 B
        const int tok0 = bid * 32;

        // ---- phase A: out-proj GEMM ----
        {
            const unsigned short* A = (const unsigned short*)attb;
            const unsigned short* W = (const unsigned short*)Wpt;
            short8 bfr[2][4];
            #pragma unroll
            for (int tt = 0; tt < 2; ++tt)
                #pragma unroll
                for (int ks = 0; ks < 4; ++ks)
                    bfr[tt][ks] = *(const short8*)(A + (size_t)(tok0 + tt * 16 + sL) * 128 + ks * 32 + quad * 8);

            f32x4 acc[2][2];
            #pragma unroll
            for (int ci = 0; ci < 2; ++ci)
                #pragma unroll
                for (int tt = 0; tt < 2; ++tt)
                    acc[ci][tt] = (f32x4){0.f, 0.f, 0.f, 0.f};

            #pragma unroll
            for (int ks = 0; ks < 4; ++ks) {
                short8 aW[2];
                #pragma unroll
                for (int ci = 0; ci < 2; ++ci)
                    aW[ci] = *(const short8*)(W + (size_t)((w * 2 + ci) * 16 + sL) * 128 + ks * 32 + quad * 8);
                #pragma unroll
                for (int ci = 0; ci < 2; ++ci)
                    #pragma unroll
                    for (int tt = 0; tt < 2; ++tt)
                        acc[ci][tt] = __builtin_amdgcn_mfma_f32_16x16x32_bf16(aW[ci], bfr[tt][ks], acc[ci][tt], 0, 0, 0);
            }
            #pragma unroll
            for (int ci = 0; ci < 2; ++ci) {
                const int n0 = (w * 2 + ci) * 16 + quad * 4;
                const float4 bb = *(const float4*)(bp + n0);
                #pragma unroll
                for (int tt = 0; tt < 2; ++tt) {
                    float4 v;
                    v.x = acc[ci][tt][0] + bb.x; v.y = acc[ci][tt][1] + bb.y;
                    v.z = acc[ci][tt][2] + bb.z; v.w = acc[ci][tt][3] + bb.w;
                    *(float4*)(&ys[tt * 16 + sL][n0]) = v;
                }
            }
        }
        __syncthreads();

        // ---- phase B: +x residual, LN1 ----
        const int tok = tid >> 3;
        const int l8  = tid & 7;
        const int c0  = l8 * 16;
        {
            float vals[16];
            float s = 0.f, s2 = 0.f;
            #pragma unroll
            for (int ch = 0; ch < 4; ++ch) {
                const float4 ly = *(const float4*)&ys[tok][c0 + ch * 4];
                const float4 gx = *(const float4*)(x + (size_t)(tok0 + tok) * 128 + c0 + ch * 4);
                vals[ch*4+0] = ly.x + gx.x; vals[ch*4+1] = ly.y + gx.y;
                vals[ch*4+2] = ly.z + gx.z; vals[ch*4+3] = ly.w + gx.w;
                #pragma unroll
                for (int j = 0; j < 4; ++j) { s += vals[ch*4+j]; s2 += vals[ch*4+j] * vals[ch*4+j]; }
            }
            #pragma unroll
            for (int off = 1; off <= 4; off <<= 1) {
                s  += __shfl_xor(s, off, 8);
                s2 += __shfl_xor(s2, off, 8);
            }
            const float mean = s * (1.0f / 128.0f);
            const float var  = s2 * (1.0f / 128.0f) - mean * mean;
            const float rstd = rsqrtf(var + 1e-5f);
            #pragma unroll
            for (int ch = 0; ch < 4; ++ch) {
                const float4 gg = *(const float4*)(g1 + c0 + ch * 4);
                const float4 bb = *(const float4*)(be1 + c0 + ch * 4);
                float ln0 = (vals[ch*4+0] - mean) * rstd * gg.x + bb.x;
                float ln1v = (vals[ch*4+1] - mean) * rstd * gg.y + bb.y;
                float ln2v = (vals[ch*4+2] - mean) * rstd * gg.z + bb.z;
                float ln3 = (vals[ch*4+3] - mean) * rstd * gg.w + bb.w;
                ys[tok][c0 + ch*4 + 0] = ln0;
                ys[tok][c0 + ch*4 + 1] = ln1v;
                ys[tok][c0 + ch*4 + 2] = ln2v;
                ys[tok][c0 + ch*4 + 3] = ln3;
                us4 lb;
                lb[0] = f2bf(ln0); lb[1] = f2bf(ln1v); lb[2] = f2bf(ln2v); lb[3] = f2bf(ln3);
                *(us4*)(l1b + tok * 136 + c0 + ch * 4) = lb;
            }
        }
        __syncthreads();

        // ---- phase C: mlp1 GEMM + fast GELU -> midb ----
        {
            const unsigned short* W = (const unsigned short*)W1t;
            short8 bl[2][4];
            #pragma unroll
            for (int tt = 0; tt < 2; ++tt)
                #pragma unroll
                for (int ks = 0; ks < 4; ++ks)
                    bl[tt][ks] = *(const short8*)(l1b + (tt * 16 + sL) * 136 + ks * 32 + quad * 8);

            f32x4 acc[8][2];
            #pragma unroll
            for (int ci = 0; ci < 8; ++ci)
                #pragma unroll
                for (int tt = 0; tt < 2; ++tt)
                    acc[ci][tt] = (f32x4){0.f, 0.f, 0.f, 0.f};

            #pragma unroll
            for (int ks = 0; ks < 4; ++ks) {
                short8 aW[8];
                #pragma unroll
                for (int ci = 0; ci < 8; ++ci)
                    aW[ci] = *(const short8*)(W + (size_t)((w * 8 + ci) * 16 + sL) * 128 + ks * 32 + quad * 8);
                #pragma unroll
                for (int ci = 0; ci < 8; ++ci)
                    #pragma unroll
                    for (int tt = 0; tt < 2; ++tt)
                        acc[ci][tt] = __builtin_amdgcn_mfma_f32_16x16x32_bf16(aW[ci], bl[tt][ks], acc[ci][tt], 0, 0, 0);
            }
            #pragma unroll
            for (int ci = 0; ci < 8; ++ci) {
                const int n0 = (w * 8 + ci) * 16 + quad * 4;
                const float4 bb = *(const float4*)(b1 + n0);
                #pragma unroll
                for (int tt = 0; tt < 2; ++tt) {
                    us4 v;
                    v[0] = f2bf(fast_gelu(acc[ci][tt][0] + bb.x));
                    v[1] = f2bf(fast_gelu(acc[ci][tt][1] + bb.y));
                    v[2] = f2bf(fast_gelu(acc[ci][tt][2] + bb.z));
                    v[3] = f2bf(fast_gelu(acc[ci][tt][3] + bb.w));
                    *(us4*)(midb + (tt * 16 + sL) * 528 + n0) = v;
                }
            }
        }
        __syncthreads();

        // ---- phase D: mlp2 GEMM ----
        f32x4 acc2[2][2];
        #pragma unroll
        for (int ci = 0; ci < 2; ++ci)
            #pragma unroll
            for (int tt = 0; tt < 2; ++tt)
                acc2[ci][tt] = (f32x4){0.f, 0.f, 0.f, 0.f};
        {
            const unsigned short* W = (const unsigned short*)W2t;
            #pragma unroll
            for (int ks = 0; ks < 16; ++ks) {
                short8 bm0 = *(const short8*)(midb + (size_t)sL * 528 + ks * 32 + quad * 8);
                short8 bm1 = *(const short8*)(midb + (size_t)(16 + sL) * 528 + ks * 32 + quad * 8);
                short8 aW0 = *(const short8*)(W + (size_t)((w * 2) * 16 + sL) * 512 + ks * 32 + quad * 8);
                short8 aW1 = *(const short8*)(W + (size_t)((w * 2 + 1) * 16 + sL) * 512 + ks * 32 + quad * 8);
                acc2[0][0] = __builtin_amdgcn_mfma_f32_16x16x32_bf16(aW0, bm0, acc2[0][0], 0, 0, 0);
                acc2[0][1] = __builtin_amdgcn_mfma_f32_16x16x32_bf16(aW0, bm1, acc2[0][1], 0, 0, 0);
                acc2[1][0] = __builtin_amdgcn_mfma_f32_16x16x32_bf16(aW1, bm0, acc2[1][0], 0, 0, 0);
                acc2[1][1] = __builtin_amdgcn_mfma_f32_16x16x32_bf16(aW1, bm1, acc2[1][1], 0, 0, 0);
            }
        }
        __syncthreads();                         // all midb reads done
        float* ys2 = (float*)midb;               // alias: 32 x 132 f32
        #pragma unroll
        for (int ci = 0; ci < 2; ++ci) {
            const int n0 = (w * 2 + ci) * 16 + quad * 4;
            const float4 bb = *(const float4*)(b2 + n0);
            #pragma unroll
            for (int tt = 0; tt < 2; ++tt) {
                float4 v;
                v.x = acc2[ci][tt][0] + bb.x; v.y = acc2[ci][tt][1] + bb.y;
                v.z = acc2[ci][tt][2] + bb.z; v.w = acc2[ci][tt][3] + bb.w;
                *(float4*)(ys2 + (tt * 16 + sL) * 132 + n0) = v;
            }
        }
        __syncthreads();

        // ---- phase E: +ln1 residual, LN2 -> out ----
        {
            float vals[16];
            float s = 0.f, s2 = 0.f;
            #pragma unroll
            for (int ch = 0; ch < 4; ++ch) {
                const float4 ly = *(const float4*)(ys2 + tok * 132 + c0 + ch * 4);
                const float4 gx = *(const float4*)&ys[tok][c0 + ch * 4];
                vals[ch*4+0] = ly.x + gx.x; vals[ch*4+1] = ly.y + gx.y;
                vals[ch*4+2] = ly.z + gx.z; vals[ch*4+3] = ly.w + gx.w;
                #pragma unroll
                for (int j = 0; j < 4; ++j) { s += vals[ch*4+j]; s2 += vals[ch*4+j] * vals[ch*4+j]; }
            }
            #pragma unroll
            for (int off = 1; off <= 4; off <<= 1) {
                s  += __shfl_xor(s, off, 8);
                s2 += __shfl_xor(s2, off, 8);
            }
            const float mean = s * (1.0f / 128.0f);
            const float var  = s2 * (1.0f / 128.0f) - mean * mean;
            const float rstd = rsqrtf(var + 1e-5f);
            #pragma unroll
            for (int ch = 0; ch < 4; ++ch) {
                const float4 gg = *(const float4*)(g2 + c0 + ch * 4);
                const float4 bb = *(const float4*)(be2 + c0 + ch * 4);
                float4 ln;
                ln.x = (vals[ch*4+0] - mean) * rstd * gg.x + bb.x;
                ln.y = (vals[ch*4+1] - mean) * rstd * gg.y + bb.y;
                ln.z = (vals[ch*4+2] - mean) * rstd * gg.z + bb.z;
                ln.w = (vals[ch*4+3] - mean) * rstd * gg.w + bb.w;
                *(float4*)(out + (size_t)(tok0 + tok) * 128 + c0 + ch * 4) = ln;
            }
        }
    }
}

// ----------------------------------------------------------------- launcher --
extern "C" void kernel_launch(void* const* d_in, const int* in_sizes, int n_in,
                              void* d_out, int out_size, void* d_ws, size_t ws_size,
                              hipStream_t stream)
{
    (void)in_sizes; (void)n_in; (void)out_size; (void)ws_size;
    const float* x   = (const float*)d_in[0];
    const float* Wq  = (const float*)d_in[1];
    const float* bq  = (const float*)d_in[2];
    const float* Wk  = (const float*)d_in[3];
    const float* bk  = (const float*)d_in[4];
    const float* Wv  = (const float*)d_in[5];
    const float* bv  = (const float*)d_in[6];
    const float* Wp  = (const float*)d_in[7];
    const float* bp  = (const float*)d_in[8];
    const float* W1  = (const float*)d_in[9];
    const float* b1  = (const float*)d_in[10];
    const float* W2  = (const float*)d_in[11];
    const float* b2  = (const float*)d_in[12];
    const float* g1  = (const float*)d_in[13];
    const float* be1 = (const float*)d_in[14];
    const float* g2  = (const float*)d_in[15];
    const float* be2 = (const float*)d_in[16];
    float* out = (float*)d_out;

    char* wsb = (char*)d_ws;
    // ws map: qb 0-4M | kb 4-8M | vtb 8-12M | attb 12-16M | weights @16M
    // barriers @ 16M + 512K
    __hip_bfloat16* qb   = (__hip_bfloat16*)wsb;
    __hip_bfloat16* kb   = (__hip_bfloat16*)(wsb + (4u  << 20));
    __hip_bfloat16* vtb  = (__hip_bfloat16*)(wsb + (8u  << 20));
    __hip_bfloat16* attb = (__hip_bfloat16*)(wsb + (12u << 20));
    __hip_bfloat16* Wqkvt= (__hip_bfloat16*)(wsb + (16u << 20));
    __hip_bfloat16* Wpt  = (__hip_bfloat16*)(wsb + (16u << 20) + (96u  << 10));
    __hip_bfloat16* W1t  = (__hip_bfloat16*)(wsb + (16u << 20) + (128u << 10));
    __hip_bfloat16* W2t  = (__hip_bfloat16*)(wsb + (16u << 20) + (256u << 10));
    unsigned* bars       = (unsigned*)(wsb + (16u << 20) + (512u << 10));

    hipMemsetAsync(bars, 0, 256, stream);
    k_fused<<<NBLK, 256, 0, stream>>>(
        x, Wq, bq, Wk, bk, Wv, bv, Wp, bp, W1, b1, W2, b2,
        g1, be1, g2, be2,
        Wqkvt, Wpt, W1t, W2t, qb, kb, vtb, attb, bars, out);
}

// Round 7
// 154.440 us; speedup vs baseline: 2.0347x; 2.0347x over previous
//
#include <hip/hip_runtime.h>
#include <hip/hip_bf16.h>
#include <math.h>

constexpr int NB  = 16;
constexpr int NT  = 1024;
constexpr int ND  = 128;
constexpr int NH  = 8;
constexpr int NHS = 16;
constexpr int NDH = 512;
constexpr long NBT = (long)NB * NT;   // 16384 tokens

typedef __attribute__((ext_vector_type(8))) short short8;
typedef __attribute__((ext_vector_type(4))) float f32x4;
typedef __attribute__((ext_vector_type(16))) float f32x16;
typedef __attribute__((ext_vector_type(4))) unsigned short us4;

__device__ __forceinline__ unsigned short f2bf(float f) {
    __hip_bfloat16 h = __float2bfloat16(f);
    return *(unsigned short*)&h;
}

// f32[8] -> bf16x8 fragment (RNE packed converts), contiguous source
__device__ __forceinline__ short8 cvt8(const float* p) {
    const float4 f0 = *(const float4*)p;
    const float4 f1 = *(const float4*)(p + 4);
    union { short8 s; __hip_bfloat162 h[4]; } u;
    u.h[0] = __float22bfloat162_rn(make_float2(f0.x, f0.y));
    u.h[1] = __float22bfloat162_rn(make_float2(f0.z, f0.w));
    u.h[2] = __float22bfloat162_rn(make_float2(f1.x, f1.y));
    u.h[3] = __float22bfloat162_rn(make_float2(f1.z, f1.w));
    return u.s;
}

// f32[8] -> bf16x8 fragment, stride-16-float source (in-flight W transpose).
// Lane sL reads consecutive floats across the wave (s = fastest dim of W):
// the 8 dword loads per lane are 64B-coalesced across the 16-lane group.
__device__ __forceinline__ short8 cvt8s(const float* p) {
    union { short8 s; __hip_bfloat162 h[4]; } u;
    #pragma unroll
    for (int jj = 0; jj < 4; ++jj)
        u.h[jj] = __float22bfloat162_rn(make_float2(p[(2 * jj) * 16], p[(2 * jj + 1) * 16]));
    return u.s;
}

// fast GELU (tanh form, exp2-based): max |err| ~1e-3, under bf16 noise.
__device__ __forceinline__ float fast_gelu(float y) {
    const float t = y * y;
    const float u = __builtin_fmaf(y * 0.044715f, t, y);
    const float e = __builtin_amdgcn_exp2f(u * -2.302118131f); // -2*sqrt(2/pi)*log2(e)
    return y * __builtin_amdgcn_rcpf(1.0f + e);
}

// ------------------------------------------------------- K1: QKV (MFMA) -----
// blocks 0..511: 32 tokens each, transposed-D GEMM. A-fragments are built
// DIRECTLY from Wq/Wk/Wv f32 (strided cvt8s) — no k_prep kernel, no Wqkvt.
// blocks 512..655: Wpt/W1t/W2t transposes (consumed by k_tail, 2 launches on).
__global__ __launch_bounds__(256) void k_qkv(
    const float* __restrict__ x,
    const float* __restrict__ Wq, const float* __restrict__ Wk,
    const float* __restrict__ Wv,
    const float* __restrict__ bq, const float* __restrict__ bk,
    const float* __restrict__ bv,
    const float* __restrict__ Wp, const float* __restrict__ W1,
    const float* __restrict__ W2,
    __hip_bfloat16* __restrict__ Wpt, __hip_bfloat16* __restrict__ W1t,
    __hip_bfloat16* __restrict__ W2t,
    __hip_bfloat16* __restrict__ qo, __hip_bfloat16* __restrict__ ko,
    __hip_bfloat16* __restrict__ vo)
{
    __shared__ __align__(16) unsigned short st[32 * 392];
    const int tid = threadIdx.x;

    if (blockIdx.x >= 512) {              // fused weight-prep tail
        const int blk = blockIdx.x - 512 + 48;   // 48..191
        us4 v;
        if (blk < 64) {                   // Wpt: 16384
            const int i0 = (blk - 48) * 1024 + tid * 4;
            const int n = i0 >> 7, d0 = i0 & 127;
            #pragma unroll
            for (int j = 0; j < 4; ++j) v[j] = f2bf(Wp[(d0 + j) * 128 + n]);
            *(us4*)((unsigned short*)Wpt + i0) = v;
        } else if (blk < 128) {           // W1t: 65536
            const int i0 = (blk - 64) * 1024 + tid * 4;
            const int n = i0 >> 7, d0 = i0 & 127;
            #pragma unroll
            for (int j = 0; j < 4; ++j) v[j] = f2bf(W1[(d0 + j) * 512 + n]);
            *(us4*)((unsigned short*)W1t + i0) = v;
        } else {                          // W2t: 65536
            const int i0 = (blk - 128) * 1024 + tid * 4;
            const int n = i0 >> 9, k0 = i0 & 511;
            #pragma unroll
            for (int j = 0; j < 4; ++j) v[j] = f2bf(W2[(k0 + j) * 128 + n]);
            *(us4*)((unsigned short*)W2t + i0) = v;
        }
        return;
    }

    const int w    = tid >> 6;
    const int lane = tid & 63;
    const int sL   = lane & 15;
    const int quad = lane >> 4;
    const int tok0 = blockIdx.x * 32;

    // B-fragments from x: lane sL = token column
    short8 bx[2][4];
    #pragma unroll
    for (int tt = 0; tt < 2; ++tt)
        #pragma unroll
        for (int ks = 0; ks < 4; ++ks)
            bx[tt][ks] = cvt8(x + (size_t)(tok0 + tt * 16 + sL) * 128 + ks * 32 + quad * 8);

    f32x4 acc[6][2];                      // [ci = n-tile][tt = tok-tile]
    #pragma unroll
    for (int ci = 0; ci < 6; ++ci)
        #pragma unroll
        for (int tt = 0; tt < 2; ++tt)
            acc[ci][tt] = (f32x4){0.f, 0.f, 0.f, 0.f};

    #pragma unroll
    for (int ks = 0; ks < 4; ++ks) {
        short8 aW[6];
        #pragma unroll
        for (int ci = 0; ci < 6; ++ci) {
            const int ct = w * 6 + ci;
            const int kind = ct >> 3;          // wave-uniform
            const float* Wsec = (kind == 0) ? Wq : (kind == 1) ? Wk : Wv;
            // element j: Wsec[(ct&7)*2048 + (ks*32+quad*8+j)*16 + sL]
            aW[ci] = cvt8s(Wsec + (ct & 7) * 2048 + (ks * 32 + quad * 8) * 16 + sL);
        }
        #pragma unroll
        for (int ci = 0; ci < 6; ++ci)
            #pragma unroll
            for (int tt = 0; tt < 2; ++tt)
                acc[ci][tt] = __builtin_amdgcn_mfma_f32_16x16x32_bf16(aW[ci], bx[tt][ks], acc[ci][tt], 0, 0, 0);
    }

    const float qscale = 0.3606737602f;   // 0.25 * log2(e) folded into q
    #pragma unroll
    for (int ci = 0; ci < 6; ++ci) {
        const int ct = w * 6 + ci;
        const int kind = ct >> 3;          // wave-uniform
        const int ncc = (ct & 7) * 16 + quad * 4;   // within-section col base
        const float4 bb = *(const float4*)(((kind == 0) ? bq : (kind == 1) ? bk : bv) + ncc);
        #pragma unroll
        for (int tt = 0; tt < 2; ++tt) {
            us4 v;
            #pragma unroll
            for (int r = 0; r < 4; ++r) {
                float val = acc[ci][tt][r] + ((const float*)&bb)[r];
                if (kind == 0) val *= qscale;
                v[r] = f2bf(val);
            }
            *(us4*)(st + (tt * 16 + sL) * 392 + ct * 16 + quad * 4) = v;
        }
    }
    __syncthreads();

    const int b = tok0 >> 10, tt0 = tok0 & 1023;
    {   // q,k copy-out: thread = (h, tok); 32B contiguous each
        const int h = tid >> 5, tok = tid & 31;
        const unsigned short* sq = st + tok * 392 + h * 16;
        const unsigned short* sk = st + tok * 392 + 128 + h * 16;
        unsigned short* dq = (unsigned short*)qo + ((size_t)(b * 8 + h) * 1024 + tt0 + tok) * 16;
        unsigned short* dk = (unsigned short*)ko + ((size_t)(b * 8 + h) * 1024 + tt0 + tok) * 16;
        *(short8*)dq       = *(const short8*)sq;
        *(short8*)(dq + 8) = *(const short8*)(sq + 8);
        *(short8*)dk       = *(const short8*)sk;
        *(short8*)(dk + 8) = *(const short8*)(sk + 8);
    }
    if (tid < 128) {  // v copy-out (transposed): thread = (h,s); 64B contiguous
        const int h = tid >> 4, s = tid & 15;
        unsigned short tmp[32];
        #pragma unroll
        for (int tok = 0; tok < 32; ++tok)
            tmp[tok] = st[tok * 392 + 256 + h * 16 + s];
        unsigned short* dv = (unsigned short*)vo + ((size_t)(b * 8 + h) * 16 + s) * 1024 + tt0;
        #pragma unroll
        for (int j = 0; j < 4; ++j)
            *(short8*)(dv + j * 8) = *(const short8*)(tmp + j * 8);
    }
}

// ------------------------------------------------------------ K2: attention --
// 32x32x16-MFMA flash attention, swapped QK^T (S[k][q], q = lane col), P
// redistribution via v_cvt_pk_bf16_f32 + v_permlane32_swap_b32, no-max
// softmax, XCD-pinned (bh = blockIdx&127). tile = wave*8 + sub: per-block
// chunk totals 56..84 (1.5:1) instead of 10..130 — no straggler blocks.
// permlane32_swap(a,b): ret[0]=[a.lo32lanes|b.lo32lanes],
//                       ret[1]=[a.hi32lanes|b.hi32lanes]
__global__ __launch_bounds__(256) void k_attn(
    const __hip_bfloat16* __restrict__ qb, const __hip_bfloat16* __restrict__ kb,
    const __hip_bfloat16* __restrict__ vtb, __hip_bfloat16* __restrict__ att)
{
    __shared__ __align__(16) float stg[4][32 * 16];   // per-wave o staging
    const int bh   = blockIdx.x & 127;
    const int sub  = blockIdx.x >> 7;          // 0..7
    const int wave = threadIdx.x >> 6;
    const int lane = threadIdx.x & 63;
    const int col  = lane & 31;                // q col (QK) / s col (PV)
    const int hi   = lane >> 5;
    const int b = bh >> 3, h = bh & 7;
    const int tile = wave * 8 + sub;           // 0..31 (balanced across blocks)
    const int t0 = tile * 32;

    const unsigned short* qp = (const unsigned short*)qb  + (size_t)bh * NT * NHS;
    const unsigned short* kp = (const unsigned short*)kb  + (size_t)bh * NT * NHS;
    const unsigned short* vp = (const unsigned short*)vtb + (size_t)bh * NHS * NT;

    // Q fragment (B operand): col = q token, elems = dims hi*8..hi*8+7
    const short8 bQ = *(const short8*)(qp + (size_t)(t0 + col) * NHS + hi * 8);
    // V row pointer: s = col&15 (cols 16-31 duplicate 0-15; discarded at store)
    const unsigned short* vrow = vp + (size_t)(col & 15) * NT + hi * 8;

    f32x16 o;
    #pragma unroll
    for (int r = 0; r < 16; ++r) o[r] = 0.f;
    f32x16 zc;
    #pragma unroll
    for (int r = 0; r < 16; ++r) zc[r] = 0.f;
    float lp0 = 0.f, lp1 = 0.f, lp2 = 0.f, lp3 = 0.f;

    for (int c = 0; c <= tile; ++c) {
        const int u0 = c * 32;
        // K A-frag: row = k token (l&31), elems = dims hi*8+j
        const short8 aK  = *(const short8*)(kp + (size_t)(u0 + col) * NHS + hi * 8);
        // V B-frags: col = s, elems = k tokens; two 16-k slices
        const short8 bV0 = *(const short8*)(vrow + u0);
        const short8 bV1 = *(const short8*)(vrow + u0 + 16);

        // S[k][q]: col = q = lane&31, k = (r&3)+8*(r>>2)+4*hi
        const f32x16 sT = __builtin_amdgcn_mfma_f32_32x32x16_bf16(aK, bQ, zc, 0, 0, 0);

        float p[16];
        if (c < tile) {                        // wave-uniform: fully unmasked
            #pragma unroll
            for (int r = 0; r < 16; ++r) p[r] = __builtin_amdgcn_exp2f(sT[r]);
        } else {                               // diagonal chunk: k<=q mask
            const int kh = 4 * hi;
            #pragma unroll
            for (int r = 0; r < 16; ++r) {
                const int kc = (r & 3) + 8 * (r >> 2) + kh;
                const float e = __builtin_amdgcn_exp2f(sT[r]);
                p[r] = (kc <= col) ? e : 0.f;
            }
        }
        #pragma unroll
        for (int r = 0; r < 16; r += 4) {
            lp0 += p[r]; lp1 += p[r + 1]; lp2 += p[r + 2]; lp3 += p[r + 3];
        }

        // pack adjacent-k pairs to bf16x2 (consecutive regs = consecutive k)
        int d[8];
        #pragma unroll
        for (int i = 0; i < 8; ++i) {
            __hip_bfloat162 hh = __float22bfloat162_rn(make_float2(p[2 * i], p[2 * i + 1]));
            d[i] = *(int*)&hh;
        }
        auto s0 = __builtin_amdgcn_permlane32_swap(d[0], d[2], false, false);
        auto s1 = __builtin_amdgcn_permlane32_swap(d[1], d[3], false, false);
        auto s2 = __builtin_amdgcn_permlane32_swap(d[4], d[6], false, false);
        auto s3 = __builtin_amdgcn_permlane32_swap(d[5], d[7], false, false);
        union { int i[4]; short8 v; } A0, A1;  // P^T A-frags, k slices 0/1
        A0.i[0] = s0[0]; A0.i[1] = s1[0]; A0.i[2] = s0[1]; A0.i[3] = s1[1];
        A1.i[0] = s2[0]; A1.i[1] = s3[0]; A1.i[2] = s2[1]; A1.i[3] = s3[1];

        o = __builtin_amdgcn_mfma_f32_32x32x16_bf16(A0.v, bV0, o, 0, 0, 0);
        o = __builtin_amdgcn_mfma_f32_32x32x16_bf16(A1.v, bV1, o, 0, 0, 0);
    }

    float lp = (lp0 + lp1) + (lp2 + lp3);
    lp += __shfl_xor(lp, 32);                  // lane pair (q, q+32) -> total
    const float inv = 1.0f / lp;               // inv for q = lane&31

    // stage raw o (f32) to LDS [q][s]; normalize+convert on the read side
    float* sp = stg[wave];
    if (col < 16) {
        #pragma unroll
        for (int r = 0; r < 16; ++r) {
            const int qr = (r & 3) + 8 * (r >> 2) + 4 * hi;
            sp[qr * 16 + col] = o[r];
        }
    }
    __syncthreads();
    const float invq = __shfl(inv, lane >> 1); // lane l -> inv of q = l>>1
    const float* rp = sp + (lane >> 1) * 16 + (lane & 1) * 8;
    const float4 va = *(const float4*)rp;
    const float4 vb = *(const float4*)(rp + 4);
    union { short8 v; unsigned short u[8]; } res;
    res.u[0] = f2bf(va.x * invq); res.u[1] = f2bf(va.y * invq);
    res.u[2] = f2bf(va.z * invq); res.u[3] = f2bf(va.w * invq);
    res.u[4] = f2bf(vb.x * invq); res.u[5] = f2bf(vb.y * invq);
    res.u[6] = f2bf(vb.z * invq); res.u[7] = f2bf(vb.w * invq);
    unsigned short* dst = (unsigned short*)att +
        ((size_t)b * NT + t0 + (lane >> 1)) * ND + h * NHS + (lane & 1) * 8;
    *(short8*)dst = res.v;
}

// ------------- K3: FUSED tail: proj + LN1 + mlp1 + GELU + mlp2 + LN2 --------
// All GEMMs in transposed-D orientation: A = weight rows, B = activation rows,
// D: lane = token col, 4 consecutive features per thread -> vector LDS writes.
__global__ __launch_bounds__(256) void k_tail(
    const __hip_bfloat16* __restrict__ attb, const __hip_bfloat16* __restrict__ Wpt,
    const __hip_bfloat16* __restrict__ W1t, const __hip_bfloat16* __restrict__ W2t,
    const float* __restrict__ x, const float* __restrict__ bp,
    const float* __restrict__ g1, const float* __restrict__ be1,
    const float* __restrict__ b1, const float* __restrict__ b2,
    const float* __restrict__ g2, const float* __restrict__ be2,
    float* __restrict__ out)
{
    __shared__ float ys[32][132];                            // proj-out -> ln1f
    __shared__ __align__(16) unsigned short l1b[32 * 136];   // ln1 bf16
    __shared__ __align__(16) unsigned short midb[32 * 528];  // gelu out bf16
    const int w    = threadIdx.x >> 6;
    const int lane = threadIdx.x & 63;
    const int sL   = lane & 15;
    const int quad = lane >> 4;
    const int tok0 = blockIdx.x * 32;

    // ---- phase A: out-proj GEMM (transposed-D) ----
    {
        const unsigned short* A = (const unsigned short*)attb;
        const unsigned short* W = (const unsigned short*)Wpt;
        short8 bfr[2][4];
        #pragma unroll
        for (int tt = 0; tt < 2; ++tt)
            #pragma unroll
            for (int ks = 0; ks < 4; ++ks)
                bfr[tt][ks] = *(const short8*)(A + (size_t)(tok0 + tt * 16 + sL) * 128 + ks * 32 + quad * 8);

        f32x4 acc[2][2];                   // [ci = n-tile][tt]
        #pragma unroll
        for (int ci = 0; ci < 2; ++ci)
            #pragma unroll
            for (int tt = 0; tt < 2; ++tt)
                acc[ci][tt] = (f32x4){0.f, 0.f, 0.f, 0.f};

        #pragma unroll
        for (int ks = 0; ks < 4; ++ks) {
            short8 aW[2];
            #pragma unroll
            for (int ci = 0; ci < 2; ++ci)
                aW[ci] = *(const short8*)(W + (size_t)((w * 2 + ci) * 16 + sL) * 128 + ks * 32 + quad * 8);
            #pragma unroll
            for (int ci = 0; ci < 2; ++ci)
                #pragma unroll
                for (int tt = 0; tt < 2; ++tt)
                    acc[ci][tt] = __builtin_amdgcn_mfma_f32_16x16x32_bf16(aW[ci], bfr[tt][ks], acc[ci][tt], 0, 0, 0);
        }
        #pragma unroll
        for (int ci = 0; ci < 2; ++ci) {
            const int n0 = (w * 2 + ci) * 16 + quad * 4;
            const float4 bb = *(const float4*)(bp + n0);
            #pragma unroll
            for (int tt = 0; tt < 2; ++tt) {
                float4 v;
                v.x = acc[ci][tt][0] + bb.x; v.y = acc[ci][tt][1] + bb.y;
                v.z = acc[ci][tt][2] + bb.z; v.w = acc[ci][tt][3] + bb.w;
                *(float4*)(&ys[tt * 16 + sL][n0]) = v;
            }
        }
    }
    __syncthreads();

    // ---- phase B: +x residual, LN1 -> ys (f32) and l1b (bf16) ----
    const int tok = threadIdx.x >> 3;
    const int l8  = threadIdx.x & 7;
    const int c0  = l8 * 16;
    {
        float vals[16];
        float s = 0.f, s2 = 0.f;
        #pragma unroll
        for (int ch = 0; ch < 4; ++ch) {
            const float4 ly = *(const float4*)&ys[tok][c0 + ch * 4];
            const float4 gx = *(const float4*)(x + (size_t)(tok0 + tok) * 128 + c0 + ch * 4);
            vals[ch*4+0] = ly.x + gx.x; vals[ch*4+1] = ly.y + gx.y;
            vals[ch*4+2] = ly.z + gx.z; vals[ch*4+3] = ly.w + gx.w;
            #pragma unroll
            for (int j = 0; j < 4; ++j) { s += vals[ch*4+j]; s2 += vals[ch*4+j] * vals[ch*4+j]; }
        }
        #pragma unroll
        for (int off = 1; off <= 4; off <<= 1) {
            s  += __shfl_xor(s, off, 8);
            s2 += __shfl_xor(s2, off, 8);
        }
        const float mean = s * (1.0f / 128.0f);
        const float var  = s2 * (1.0f / 128.0f) - mean * mean;
        const float rstd = rsqrtf(var + 1e-5f);
        #pragma unroll
        for (int ch = 0; ch < 4; ++ch) {
            const float4 gg = *(const float4*)(g1 + c0 + ch * 4);
            const float4 bb = *(const float4*)(be1 + c0 + ch * 4);
            float ln0 = (vals[ch*4+0] - mean) * rstd * gg.x + bb.x;
            float ln1v = (vals[ch*4+1] - mean) * rstd * gg.y + bb.y;
            float ln2v = (vals[ch*4+2] - mean) * rstd * gg.z + bb.z;
            float ln3 = (vals[ch*4+3] - mean) * rstd * gg.w + bb.w;
            ys[tok][c0 + ch*4 + 0] = ln0;
            ys[tok][c0 + ch*4 + 1] = ln1v;
            ys[tok][c0 + ch*4 + 2] = ln2v;
            ys[tok][c0 + ch*4 + 3] = ln3;
            us4 lb;
            lb[0] = f2bf(ln0); lb[1] = f2bf(ln1v); lb[2] = f2bf(ln2v); lb[3] = f2bf(ln3);
            *(us4*)(l1b + tok * 136 + c0 + ch * 4) = lb;
        }
    }
    __syncthreads();

    // ---- phase C: mlp1 GEMM (transposed-D) + fast GELU -> midb (LDS) ----
    {
        const unsigned short* W = (const unsigned short*)W1t;
        short8 bl[2][4];
        #pragma unroll
        for (int tt = 0; tt < 2; ++tt)
            #pragma unroll
            for (int ks = 0; ks < 4; ++ks)
                bl[tt][ks] = *(const short8*)(l1b + (tt * 16 + sL) * 136 + ks * 32 + quad * 8);

        f32x4 acc[8][2];
        #pragma unroll
        for (int ci = 0; ci < 8; ++ci)
            #pragma unroll
            for (int tt = 0; tt < 2; ++tt)
                acc[ci][tt] = (f32x4){0.f, 0.f, 0.f, 0.f};

        #pragma unroll
        for (int ks = 0; ks < 4; ++ks) {
            short8 aW[8];
            #pragma unroll
            for (int ci = 0; ci < 8; ++ci)
                aW[ci] = *(const short8*)(W + (size_t)((w * 8 + ci) * 16 + sL) * 128 + ks * 32 + quad * 8);
            #pragma unroll
            for (int ci = 0; ci < 8; ++ci)
                #pragma unroll
                for (int tt = 0; tt < 2; ++tt)
                    acc[ci][tt] = __builtin_amdgcn_mfma_f32_16x16x32_bf16(aW[ci], bl[tt][ks], acc[ci][tt], 0, 0, 0);
        }
        #pragma unroll
        for (int ci = 0; ci < 8; ++ci) {
            const int n0 = (w * 8 + ci) * 16 + quad * 4;
            const float4 bb = *(const float4*)(b1 + n0);
            #pragma unroll
            for (int tt = 0; tt < 2; ++tt) {
                us4 v;
                v[0] = f2bf(fast_gelu(acc[ci][tt][0] + bb.x));
                v[1] = f2bf(fast_gelu(acc[ci][tt][1] + bb.y));
                v[2] = f2bf(fast_gelu(acc[ci][tt][2] + bb.z));
                v[3] = f2bf(fast_gelu(acc[ci][tt][3] + bb.w));
                *(us4*)(midb + (tt * 16 + sL) * 528 + n0) = v;
            }
        }
    }
    __syncthreads();

    // ---- phase D: mlp2 GEMM (transposed-D) ----
    f32x4 acc2[2][2];
    #pragma unroll
    for (int ci = 0; ci < 2; ++ci)
        #pragma unroll
        for (int tt = 0; tt < 2; ++tt)
            acc2[ci][tt] = (f32x4){0.f, 0.f, 0.f, 0.f};
    {
        const unsigned short* W = (const unsigned short*)W2t;
        #pragma unroll
        for (int ks = 0; ks < 16; ++ks) {
            short8 bm0 = *(const short8*)(midb + (size_t)sL * 528 + ks * 32 + quad * 8);
            short8 bm1 = *(const short8*)(midb + (size_t)(16 + sL) * 528 + ks * 32 + quad * 8);
            short8 aW0 = *(const short8*)(W + (size_t)((w * 2) * 16 + sL) * 512 + ks * 32 + quad * 8);
            short8 aW1 = *(const short8*)(W + (size_t)((w * 2 + 1) * 16 + sL) * 512 + ks * 32 + quad * 8);
            acc2[0][0] = __builtin_amdgcn_mfma_f32_16x16x32_bf16(aW0, bm0, acc2[0][0], 0, 0, 0);
            acc2[0][1] = __builtin_amdgcn_mfma_f32_16x16x32_bf16(aW0, bm1, acc2[0][1], 0, 0, 0);
            acc2[1][0] = __builtin_amdgcn_mfma_f32_16x16x32_bf16(aW1, bm0, acc2[1][0], 0, 0, 0);
            acc2[1][1] = __builtin_amdgcn_mfma_f32_16x16x32_bf16(aW1, bm1, acc2[1][1], 0, 0, 0);
        }
    }
    __syncthreads();                         // all midb reads done
    float* ys2 = (float*)midb;               // alias: 32 x 132 f32 (16.9 KB)
    #pragma unroll
    for (int ci = 0; ci < 2; ++ci) {
        const int n0 = (w * 2 + ci) * 16 + quad * 4;
        const float4 bb = *(const float4*)(b2 + n0);
        #pragma unroll
        for (int tt = 0; tt < 2; ++tt) {
            float4 v;
            v.x = acc2[ci][tt][0] + bb.x; v.y = acc2[ci][tt][1] + bb.y;
            v.z = acc2[ci][tt][2] + bb.z; v.w = acc2[ci][tt][3] + bb.w;
            *(float4*)(ys2 + (tt * 16 + sL) * 132 + n0) = v;
        }
    }
    __syncthreads();

    // ---- phase E: +ln1 residual, LN2 -> out ----
    {
        float vals[16];
        float s = 0.f, s2 = 0.f;
        #pragma unroll
        for (int ch = 0; ch < 4; ++ch) {
            const float4 ly = *(const float4*)(ys2 + tok * 132 + c0 + ch * 4);
            const float4 gx = *(const float4*)&ys[tok][c0 + ch * 4];
            vals[ch*4+0] = ly.x + gx.x; vals[ch*4+1] = ly.y + gx.y;
            vals[ch*4+2] = ly.z + gx.z; vals[ch*4+3] = ly.w + gx.w;
            #pragma unroll
            for (int j = 0; j < 4; ++j) { s += vals[ch*4+j]; s2 += vals[ch*4+j] * vals[ch*4+j]; }
        }
        #pragma unroll
        for (int off = 1; off <= 4; off <<= 1) {
            s  += __shfl_xor(s, off, 8);
            s2 += __shfl_xor(s2, off, 8);
        }
        const float mean = s * (1.0f / 128.0f);
        const float var  = s2 * (1.0f / 128.0f) - mean * mean;
        const float rstd = rsqrtf(var + 1e-5f);
        #pragma unroll
        for (int ch = 0; ch < 4; ++ch) {
            const float4 gg = *(const float4*)(g2 + c0 + ch * 4);
            const float4 bb = *(const float4*)(be2 + c0 + ch * 4);
            float4 ln;
            ln.x = (vals[ch*4+0] - mean) * rstd * gg.x + bb.x;
            ln.y = (vals[ch*4+1] - mean) * rstd * gg.y + bb.y;
            ln.z = (vals[ch*4+2] - mean) * rstd * gg.z + bb.z;
            ln.w = (vals[ch*4+3] - mean) * rstd * gg.w + bb.w;
            *(float4*)(out + (size_t)(tok0 + tok) * 128 + c0 + ch * 4) = ln;
        }
    }
}

// ----------------------------------------------------------------- launcher --
extern "C" void kernel_launch(void* const* d_in, const int* in_sizes, int n_in,
                              void* d_out, int out_size, void* d_ws, size_t ws_size,
                              hipStream_t stream)
{
    (void)in_sizes; (void)n_in; (void)out_size; (void)ws_size;
    const float* x   = (const float*)d_in[0];
    const float* Wq  = (const float*)d_in[1];
    const float* bq  = (const float*)d_in[2];
    const float* Wk  = (const float*)d_in[3];
    const float* bk  = (const float*)d_in[4];
    const float* Wv  = (const float*)d_in[5];
    const float* bv  = (const float*)d_in[6];
    const float* Wp  = (const float*)d_in[7];
    const float* bp  = (const float*)d_in[8];
    const float* W1  = (const float*)d_in[9];
    const float* b1  = (const float*)d_in[10];
    const float* W2  = (const float*)d_in[11];
    const float* b2  = (const float*)d_in[12];
    const float* g1  = (const float*)d_in[13];
    const float* be1 = (const float*)d_in[14];
    const float* g2  = (const float*)d_in[15];
    const float* be2 = (const float*)d_in[16];
    float* out = (float*)d_out;

    char* wsb = (char*)d_ws;
    // ws map: qb 0-4M | kb 4-8M | vtb 8-12M | attb 12-16M | weights @16M
    __hip_bfloat16* qb   = (__hip_bfloat16*)wsb;
    __hip_bfloat16* kb   = (__hip_bfloat16*)(wsb + (4u  << 20));
    __hip_bfloat16* vtb  = (__hip_bfloat16*)(wsb + (8u  << 20));
    __hip_bfloat16* attb = (__hip_bfloat16*)(wsb + (12u << 20));
    __hip_bfloat16* Wpt  = (__hip_bfloat16*)(wsb + (16u << 20) + (96u  << 10));
    __hip_bfloat16* W1t  = (__hip_bfloat16*)(wsb + (16u << 20) + (128u << 10));
    __hip_bfloat16* W2t  = (__hip_bfloat16*)(wsb + (16u << 20) + (256u << 10));

    k_qkv <<<656,  256, 0, stream>>>(x, Wq, Wk, Wv, bq, bk, bv, Wp, W1, W2,
                                     Wpt, W1t, W2t, qb, kb, vtb);
    k_attn<<<1024, 256, 0, stream>>>(qb, kb, vtb, attb);
    k_tail<<<512,  256, 0, stream>>>(attb, Wpt, W1t, W2t, x, bp, g1, be1,
                                     b1, b2, g2, be2, out);
}